// Round 1
// baseline (523.518 us; speedup 1.0000x reference)
//
#include <hip/hip_runtime.h>

// IIR filtfilt via overlap-chunk parallelization.
// Max pole radius ~0.924 -> warm-up of WARM samples truncates initial-state
// error to ~0.924^WARM (~2e-9 rel at WARM=256), far below the 6e-2 threshold.
constexpr int CHUNK = 512;   // output samples per thread
constexpr int WARM  = 256;   // warm-up samples (discarded)

// DIR=0: forward in time. DIR=1: process time-reversed sequence
// (reads/writes at mirrored positions T-1-t).
template <int DIR>
__global__ __launch_bounds__(256) void iir_pass(
    const float* __restrict__ x, float* __restrict__ y,
    const float* __restrict__ bc, const float* __restrict__ ac,
    int T, int chunksPerRow)
{
    const int gid   = blockIdx.x * blockDim.x + threadIdx.x;
    const int row   = gid / chunksPerRow;
    const int chunk = gid - row * chunksPerRow;

    const float* __restrict__ xr = x + (size_t)row * T;
    float* __restrict__       yr = y + (size_t)row * T;

    // Normalize coefficients (a[0] is 1.0 for np.poly, but be exact).
    const float inv = 1.0f / ac[0];
    const float b0  = bc[0] * inv;
    float bt[8], nat[8];
#pragma unroll
    for (int i = 0; i < 8; ++i) {
        bt[i]  = bc[i + 1] * inv;
        nat[i] = -(ac[i + 1] * inv);
    }

    // DF2T state, zero-initialized (matches reference zero initial state;
    // chunk 0 starts exactly at t=0 so it is exact, others are warmed up).
    float z[8];
#pragma unroll
    for (int i = 0; i < 8; ++i) z[i] = 0.0f;

    const int tBase = chunk * CHUNK;
    const int tEnd  = tBase + CHUNK;
    int t = tBase - WARM;
    if (t < 0) t = 0;           // chunk 0: zero input+zero state == exact skip

    auto ld = [&](int tg) -> float4 {
        const float* p = (DIR == 0) ? (xr + tg) : (xr + (T - 4 - tg));
        return *(const float4*)p;
    };

    auto step = [&](float xv) -> float {
        const float yv = fmaf(b0, xv, z[0]);
#pragma unroll
        for (int i = 0; i < 7; ++i)
            z[i] = fmaf(nat[i], yv, fmaf(bt[i], xv, z[i + 1]));
        z[7] = fmaf(nat[7], yv, bt[7] * xv);
        return yv;
    };

    // Software-pipelined: prefetch next float4 group before computing current.
    float4 v = ld(t);
    for (; t < tEnd; t += 4) {
        const int tn = t + 4;
        float4 vn;
        if (tn < tEnd) vn = ld(tn);

        float xs0, xs1, xs2, xs3;
        if (DIR == 0) { xs0 = v.x; xs1 = v.y; xs2 = v.z; xs3 = v.w; }
        else          { xs0 = v.w; xs1 = v.z; xs2 = v.y; xs3 = v.x; }

        const float y0 = step(xs0);
        const float y1 = step(xs1);
        const float y2 = step(xs2);
        const float y3 = step(xs3);

        if (t >= tBase) {
            float4 o;
            if (DIR == 0) {
                o.x = y0; o.y = y1; o.z = y2; o.w = y3;
                *(float4*)(yr + t) = o;
            } else {
                o.x = y3; o.y = y2; o.z = y1; o.w = y0;
                *(float4*)(yr + (T - 4 - t)) = o;
            }
        }
        v = vn;
    }
}

extern "C" void kernel_launch(void* const* d_in, const int* in_sizes, int n_in,
                              void* d_out, int out_size, void* d_ws, size_t ws_size,
                              hipStream_t stream)
{
    const float* x = (const float*)d_in[0];
    const float* b = (const float*)d_in[1];
    const float* a = (const float*)d_in[2];
    float* out = (float*)d_out;
    float* tmp = (float*)d_ws;   // forward-pass intermediate: out_size floats

    const int T = 65536;
    const int B = in_sizes[0] / T;
    const int chunksPerRow = T / CHUNK;       // 128
    const int totalThreads = B * chunksPerRow; // 65536

    dim3 block(256);
    dim3 grid(totalThreads / 256);

    iir_pass<0><<<grid, block, 0, stream>>>(x,   tmp, b, a, T, chunksPerRow);
    iir_pass<1><<<grid, block, 0, stream>>>(tmp, out, b, a, T, chunksPerRow);
}

// Round 2
// 403.414 us; speedup vs baseline: 1.2977x; 1.2977x over previous
//
#include <hip/hip_runtime.h>

// IIR filtfilt via overlap-chunk parallelization.
// Max pole radius ~0.924 -> WARM=192 warm-up truncates initial-state error to
// ~0.924^192 ~ 2.5e-7 relative, far below the 6e-2 threshold.
// R2: CHUNK 512->256 (8 waves/CU) + 4-deep float4 prefetch pipeline to cover
// ~600cyc memory latency (R1 was latency-bound: VALUBusy 10%, HBM 45%).
constexpr int CHUNK = 256;   // output samples per thread
constexpr int WARM  = 192;   // warm-up samples (discarded); multiple of 16
constexpr int BATCH = 16;    // samples per prefetch batch (4 x float4)

// DIR=0: forward in time. DIR=1: process time-reversed sequence
// (reads/writes at mirrored positions T-1-t).
template <int DIR>
__global__ __launch_bounds__(256) void iir_pass(
    const float* __restrict__ x, float* __restrict__ y,
    const float* __restrict__ bc, const float* __restrict__ ac,
    int T, int chunksPerRow)
{
    const int gid   = blockIdx.x * blockDim.x + threadIdx.x;
    const int row   = gid / chunksPerRow;
    const int chunk = gid - row * chunksPerRow;

    const float* __restrict__ xr = x + (size_t)row * T;
    float* __restrict__       yr = y + (size_t)row * T;

    // Normalize coefficients (a[0] is 1.0 for np.poly, but be exact).
    const float inv = 1.0f / ac[0];
    const float b0  = bc[0] * inv;
    float bt[8], nat[8];
#pragma unroll
    for (int i = 0; i < 8; ++i) {
        bt[i]  = bc[i + 1] * inv;
        nat[i] = -(ac[i + 1] * inv);
    }

    // DF2T state, zero-initialized (matches reference zero initial state;
    // chunk 0 starts exactly at t=0 so it is exact, others are warmed up).
    float z[8];
#pragma unroll
    for (int i = 0; i < 8; ++i) z[i] = 0.0f;

    const int tBase = chunk * CHUNK;
    const int tEnd  = tBase + CHUNK;
    int t0 = tBase - WARM;
    if (t0 < 0) t0 = 0;         // chunk 0: zero input+zero state == exact skip

    auto ld = [&](int tg) -> float4 {
        const float* p = (DIR == 0) ? (xr + tg) : (xr + (T - 4 - tg));
        return *(const float4*)p;
    };

    auto step = [&](float xv) -> float {
        const float yv = fmaf(b0, xv, z[0]);
#pragma unroll
        for (int i = 0; i < 7; ++i)
            z[i] = fmaf(nat[i], yv, fmaf(bt[i], xv, z[i + 1]));
        z[7] = fmaf(nat[7], yv, bt[7] * xv);
        return yv;
    };

    // 4-deep prefetch pipeline: while computing a 16-sample batch, the next
    // batch's 4 float4 loads are in flight (~550cyc compute cover per batch).
    const int nb = (tEnd - t0) / BATCH;
    float4 v[4], vn[4];
#pragma unroll
    for (int j = 0; j < 4; ++j) v[j] = ld(t0 + 4 * j);

    int t = t0;
    for (int b = 0; b < nb; ++b) {
        const int tn = t + BATCH;
        if (tn < tEnd) {
#pragma unroll
            for (int j = 0; j < 4; ++j) vn[j] = ld(tn + 4 * j);
        }

#pragma unroll
        for (int j = 0; j < 4; ++j) {
            float xs0, xs1, xs2, xs3;
            if (DIR == 0) { xs0 = v[j].x; xs1 = v[j].y; xs2 = v[j].z; xs3 = v[j].w; }
            else          { xs0 = v[j].w; xs1 = v[j].z; xs2 = v[j].y; xs3 = v[j].x; }

            const float y0 = step(xs0);
            const float y1 = step(xs1);
            const float y2 = step(xs2);
            const float y3 = step(xs3);

            const int tj = t + 4 * j;
            if (tj >= tBase) {   // WARM and CHUNK are multiples of 4: aligned
                float4 o;
                if (DIR == 0) {
                    o.x = y0; o.y = y1; o.z = y2; o.w = y3;
                    *(float4*)(yr + tj) = o;
                } else {
                    o.x = y3; o.y = y2; o.z = y1; o.w = y0;
                    *(float4*)(yr + (T - 4 - tj)) = o;
                }
            }
        }

#pragma unroll
        for (int j = 0; j < 4; ++j) v[j] = vn[j];
        t = tn;
    }
}

extern "C" void kernel_launch(void* const* d_in, const int* in_sizes, int n_in,
                              void* d_out, int out_size, void* d_ws, size_t ws_size,
                              hipStream_t stream)
{
    const float* x = (const float*)d_in[0];
    const float* b = (const float*)d_in[1];
    const float* a = (const float*)d_in[2];
    float* out = (float*)d_out;
    float* tmp = (float*)d_ws;   // forward-pass intermediate: out_size floats

    const int T = 65536;
    const int B = in_sizes[0] / T;
    const int chunksPerRow = T / CHUNK;        // 256
    const int totalThreads = B * chunksPerRow; // 131072

    dim3 block(256);
    dim3 grid(totalThreads / 256);

    iir_pass<0><<<grid, block, 0, stream>>>(x,   tmp, b, a, T, chunksPerRow);
    iir_pass<1><<<grid, block, 0, stream>>>(tmp, out, b, a, T, chunksPerRow);
}